// Round 9
// baseline (226.150 us; speedup 1.0000x reference)
//
#include <hip/hip_runtime.h>
#include <stdint.h>

#define NSEQ 1032
#define CDIM 1024
#define HD 64
#define H_HEADS 16
#define BROWS 4128
#define SCALE 0.125f

typedef __attribute__((ext_vector_type(8))) short bf16x8;
typedef __attribute__((ext_vector_type(4))) float f32x4;

__device__ __forceinline__ unsigned short f2bf(float f) {
  union { float f; uint32_t u; } c; c.f = f;
  uint32_t u = c.u;
  return (unsigned short)((u + 0x7fffu + ((u >> 16) & 1u)) >> 16);
}

__device__ __forceinline__ void gl16(const void* gp, void* lp) {
  __builtin_amdgcn_global_load_lds((const __attribute__((address_space(1))) void*)gp,
                                   (__attribute__((address_space(3))) void*)lp, 16, 0, 0);
}

__global__ void convert_f32_bf16(const float* __restrict__ src, unsigned short* __restrict__ dst, int n4) {
  int i = blockIdx.x * blockDim.x + threadIdx.x;
  if (i >= n4) return;
  float4 v = ((const float4*)src)[i];
  ushort4 o;
  o.x = f2bf(v.x); o.y = f2bf(v.y); o.z = f2bf(v.z); o.w = f2bf(v.w);
  ((ushort4*)dst)[i] = o;
}

// C[m][j] = sum_k A[m][k] * Bw[j][k] + bias[j]
template<int MODE>
__global__ __launch_bounds__(256, 2) void gemm_bt(
    const unsigned short* __restrict__ A,
    const unsigned short* __restrict__ Bw,
    const float* __restrict__ bias,
    unsigned short* __restrict__ outK,
    unsigned short* __restrict__ outV,
    float* __restrict__ outF,
    int M, int K)
{
  __shared__ unsigned short As[128 * 32];
  __shared__ unsigned short Bs[128 * 32];
  const int t = threadIdx.x;
  const int w = t >> 6, lane = t & 63, lr = lane & 15, lg = lane >> 4;
  const int wr = w >> 1, wc = w & 1;
  const int m0 = blockIdx.y * 128, n0 = blockIdx.x * 128;
  f32x4 acc[4][4] = {};

  for (int ks = 0; ks < K; ks += 32) {
    #pragma unroll
    for (int q = 0; q < 2; ++q) {
      const int o = t + (q << 8);
      const int row = o >> 2, kc = o & 3;
      int ra = m0 + row; ra = ra < M ? ra : M - 1;
      gl16(A + (size_t)ra * K + ks + kc * 8, (void*)(As + o * 8));
      gl16(Bw + (size_t)(n0 + row) * K + ks + kc * 8, (void*)(Bs + o * 8));
    }
    __syncthreads();
    bf16x8 af[4], bfr[4];
    #pragma unroll
    for (int m = 0; m < 4; ++m)
      af[m] = *(const bf16x8*)(As + (wr * 64 + m * 16 + lr) * 32 + lg * 8);
    #pragma unroll
    for (int n = 0; n < 4; ++n)
      bfr[n] = *(const bf16x8*)(Bs + (wc * 64 + n * 16 + lr) * 32 + lg * 8);
    #pragma unroll
    for (int m = 0; m < 4; ++m)
      #pragma unroll
      for (int n = 0; n < 4; ++n)
        acc[m][n] = __builtin_amdgcn_mfma_f32_16x16x32_bf16(af[m], bfr[n], acc[m][n], 0, 0, 0);
    __syncthreads();
  }

  #pragma unroll
  for (int m = 0; m < 4; ++m) {
    const int rowb = m0 + wr * 64 + m * 16 + lg * 4;
    #pragma unroll
    for (int n = 0; n < 4; ++n) {
      const int col = n0 + wc * 64 + n * 16 + lr;
      const float bv = bias[col];
      #pragma unroll
      for (int r = 0; r < 4; ++r) {
        const int row = rowb + r;
        if (row >= M) continue;
        const float v = acc[m][n][r] + bv;
        if (MODE == 0) {
          const int b = row / NSEQ, nn = row - b * NSEQ;
          if (col < CDIM) {
            const int h = col >> 6, d = col & 63;
            outK[((size_t)(b * H_HEADS + h) * NSEQ + nn) * HD + d] = f2bf(v);
          } else {
            const int jj = col - CDIM, h = jj >> 6, d = jj & 63;
            outV[((size_t)(b * H_HEADS + h) * HD + d) * NSEQ + nn] = f2bf(v);
          }
        } else {
          outF[(size_t)row * CDIM + col] = v;
        }
      }
    }
  }
}

// Fused: op[b][i][h*64+d] = 0.8*(P@V)/l + 1.2*(rcs@V)
// Swapped QK^T (S^T = mfma(Kc, Kr)): lane owns ONE i-row (= lr) -> scalar lsum,
// analytic addm with 4 di-values/step. rcs loaded straight into A-fragment
// layout (no As LDS). LDS = 40KB -> 4 blocks/CU. All loop waits are counted
// vmcnt(4); raw barriers. grid 1088 XCD-swizzled.
__global__ __launch_bounds__(256, 4) void attn_fused(
    const unsigned short* __restrict__ Kb,   // [64][1032][64] bf16
    const unsigned short* __restrict__ Vt,   // [64][64][1032] bf16
    const float* __restrict__ rcs,           // [64][1032][1032] f32
    unsigned short* __restrict__ outp)       // [4128][1024] bf16
{
  __shared__ __align__(16) unsigned short Kc[2][64 * 64];  // [m][d], 16B-chunk XOR
  __shared__ __align__(16) unsigned short Vs[2][64 * 64];  // [d][m], 16B-chunk XOR
  __shared__ __align__(16) unsigned short Ps[4][16 * 64];  // per-wave [i=lr][m], chunk XOR
  const int t = threadIdx.x;
  const int w = t >> 6, lane = t & 63, lr = lane & 15, lg = lane >> 4;
  const int bid = blockIdx.x;
  const int nb = (bid & 7) * 136 + (bid >> 3);
  const int bh = nb / 17, rt = nb - bh * 17;
  const int i_base = rt * 64 + w * 16;
  const float* rbase = rcs + (size_t)bh * NSEQ * NSEQ;
  const unsigned short* kbase = Kb + (size_t)bh * NSEQ * HD;
  const unsigned short* vbase = Vt + (size_t)bh * HD * NSEQ;
  unsigned short* psw = &Ps[w][0];

  // ---- K/V gl16 descriptors (linear LDS dest, XOR-swizzled source) ----
  const unsigned short* srck[2]; int dok[2];
  const unsigned short* srcv[2]; int dov[2];
  #pragma unroll
  for (int q = 0; q < 2; ++q) {
    const int p = t + (q << 8);
    const int row = p >> 3, sch = p & 7;
    const int gch = (sch ^ row) & 7;
    srck[q] = kbase + (size_t)row * HD + gch * 8;  dok[q] = p * 8;
    srcv[q] = vbase + (size_t)row * NSEQ + gch * 8; dov[q] = p * 8;
  }
  auto stage_kv = [&](int tB, int buf) {
    #pragma unroll
    for (int q = 0; q < 2; ++q) gl16(srck[q] + (size_t)tB * HD, (void*)(Kc[buf] + dok[q]));
    #pragma unroll
    for (int q = 0; q < 2; ++q) gl16(srcv[q] + tB, (void*)(Vs[buf] + dov[q]));
  };
  auto stage_kv_tail = [&](int buf) {
    const int tB = 1024;
    #pragma unroll
    for (int q = 0; q < 2; ++q) {
      const int p = t + (q << 8);
      const int row = p >> 3, sch = p & 7;
      const int gch = (sch ^ row) & 7;
      int mrow = tB + row; if (mrow > NSEQ - 1) mrow = NSEQ - 1;
      gl16(kbase + (size_t)mrow * HD + gch * 8, (void*)(Kc[buf] + p * 8));
    }
    #pragma unroll
    for (int q = 0; q < 2; ++q) {
      const int p = t + (q << 8);
      const int row = p >> 3, sch = p & 7;
      const int gch = (sch ^ row) & 7;
      int gc = tB + gch * 8; if (gc > NSEQ - 8) gc = NSEQ - 8;
      gl16(vbase + (size_t)row * NSEQ + gc, (void*)(Vs[buf] + p * 8));
    }
  };

  // ---- rcs: direct A-fragment loads (row = i_base+lr, cols kf*32+8lg+4h) ----
  int irow_c = i_base + lr; if (irow_c > NSEQ - 1) irow_c = NSEQ - 1;
  const float* rrow = rbase + (size_t)irow_c * NSEQ;
  const int cba = 8 * lg;
  f32x4 rreg[4];
  auto ld_rcs = [&](int tB) {
    #pragma unroll
    for (int q = 0; q < 4; ++q) {
      int col = tB + (q >> 1) * 32 + cba + (q & 1) * 4;
      if (col > NSEQ - 4) col = NSEQ - 4;
      rreg[q] = *(const f32x4*)(rrow + col);
    }
  };

  // hoist Kr fragments (B-operand of swapped QK^T): rows i_base+lr, d 0..63
  bf16x8 akr[2];
  {
    const unsigned short* p = kbase + (size_t)irow_c * HD + lg * 8;
    akr[0] = *(const bf16x8*)(p);
    akr[1] = *(const bf16x8*)(p + 32);
  }

  // ---- analytic addm state (per-lane i = i_base + lr fixed) ----
  const int ii = i_base + lr;
  const int ip = ii - 8;
  const int j1 = ip & 31;
  float a_run = (float)(ip >> 5);               // i1 - 2*mt as loop runs
  const float e_lg = (lg < 2) ? 1.f : 0.f;
  const float ibad = (ii >= 8) ? 0.f : -1e30f;  // kills addm for prefix i-rows
  float cdj[16];
  #pragma unroll
  for (int fn = 0; fn < 4; ++fn)
    #pragma unroll
    for (int r = 0; r < 4; ++r) {
      const int x = 16 * fn + 4 * lg + r;
      const int m2 = (x - 8) & 31;
      const float dj = (float)(j1 - m2);
      cdj[fn * 4 + r] = -0.02f * dj * dj + ibad;
    }

  f32x4 accP[4] = {};
  f32x4 accR[4] = {};
  float lsum = 0.f;

  // prologue: stage tile 0 (K/V + rcs), drain once
  stage_kv(0, 0);
  ld_rcs(0);
  asm volatile("s_waitcnt vmcnt(0)");
  __builtin_amdgcn_s_barrier();
  __builtin_amdgcn_sched_barrier(0);

  for (int mt = 0; mt < 17; ++mt) {
    const int mB = mt * 64;
    const int cur = mt & 1, nxt = cur ^ 1;

    // A) stage next K/V tile (4 gl16)
    if (mt < 15)       stage_kv(mB + 64, nxt);
    else if (mt == 15) stage_kv_tail(nxt);
    __builtin_amdgcn_sched_barrier(0);

    // B) S^T = Kc @ Kr^T (swapped): rows m, cols i
    const unsigned short* kc = Kc[cur];
    const unsigned short* vsb = Vs[cur];
    __builtin_amdgcn_s_setprio(1);
    f32x4 st[4];
    #pragma unroll
    for (int fn = 0; fn < 4; ++fn) {
      const int row = 16 * fn + lr;
      const int r7 = row & 7;
      f32x4 z = {0.f, 0.f, 0.f, 0.f};
      bf16x8 b0 = *(const bf16x8*)(kc + row * 64 + ((lg ^ r7) & 7) * 8);
      bf16x8 b1 = *(const bf16x8*)(kc + row * 64 + (((4 + lg) ^ r7) & 7) * 8);
      z = __builtin_amdgcn_mfma_f32_16x16x32_bf16(b0, akr[0], z, 0, 0, 0);
      z = __builtin_amdgcn_mfma_f32_16x16x32_bf16(b1, akr[1], z, 0, 0, 0);
      st[fn] = z;
    }
    __builtin_amdgcn_s_setprio(0);

    // C) softmax numerators: p = exp(S^T*SCALE + addm); write bf16 pairs to Ps
    {
      const float d0 = a_run + e_lg;
      const float d1 = a_run;
      const float d2 = d0 - 1.f;
      const float d3 = d1 - 1.f;
      const float qd[4] = { -0.02f * d0 * d0, -0.02f * d1 * d1,
                            -0.02f * d2 * d2, -0.02f * d3 * d3 };
      #pragma unroll
      for (int fn = 0; fn < 4; ++fn) {
        float pv[4];
        #pragma unroll
        for (int r = 0; r < 4; ++r) {
          float ad = __expf(qd[fn] + cdj[fn * 4 + r]);
          if (mt == 0 && fn == 0) ad = (lg < 2) ? 0.f : ad;   // m<8 prefix mask
          float p = __expf(st[fn][r] * SCALE + ad);
          if (mt == 16) {                                      // m>=NSEQ mask
            if (fn > 0) p = 0.f; else p = (lg < 2) ? p : 0.f;
          }
          lsum += p;
          pv[r] = p;
        }
        const int chunk = (2 * fn + (lg >> 1)) ^ (lr & 7);
        const int off = 4 * (lg & 1);
        uint32_t w0 = (uint32_t)f2bf(pv[0]) | ((uint32_t)f2bf(pv[1]) << 16);
        uint32_t w1 = (uint32_t)f2bf(pv[2]) | ((uint32_t)f2bf(pv[3]) << 16);
        *(uint32_t*)(psw + lr * 64 + chunk * 8 + off)     = w0;
        *(uint32_t*)(psw + lr * 64 + chunk * 8 + off + 2) = w1;
      }
      a_run -= 2.f;
    }

    // D) pack rcs A-fragments from rreg (compiler waits the 4 rcs loads only)
    bf16x8 af[2];
    {
      if (mt == 16) {
        #pragma unroll
        for (int q = 0; q < 4; ++q) {
          const bool valid = (q < 2) && (lg == 0);
          if (!valid) {
            #pragma unroll
            for (int j = 0; j < 4; ++j) rreg[q][j] = 0.f;
          }
        }
      }
      #pragma unroll
      for (int kf = 0; kf < 2; ++kf) {
        f32x4 lo = rreg[2 * kf], hi = rreg[2 * kf + 1];
        bf16x8 a;
        a[0] = (short)f2bf(lo[0]); a[1] = (short)f2bf(lo[1]);
        a[2] = (short)f2bf(lo[2]); a[3] = (short)f2bf(lo[3]);
        a[4] = (short)f2bf(hi[0]); a[5] = (short)f2bf(hi[1]);
        a[6] = (short)f2bf(hi[2]); a[7] = (short)f2bf(hi[3]);
        af[kf] = a;
      }
    }
    __builtin_amdgcn_sched_barrier(0);

    // E) issue next tile's rcs loads (fly across barrier until next pack)
    if (mt < 16) ld_rcs(mB + 64);
    __builtin_amdgcn_sched_barrier(0);

    // F) PV: accP += P @ V ; accR += RCS @ V
    bf16x8 pa0 = *(const bf16x8*)(psw + lr * 64 + ((lg ^ (lr & 7)) & 7) * 8);
    bf16x8 pa1 = *(const bf16x8*)(psw + lr * 64 + (((4 + lg) ^ (lr & 7)) & 7) * 8);
    __builtin_amdgcn_s_setprio(1);
    #pragma unroll
    for (int fd = 0; fd < 4; ++fd) {
      const int row = 16 * fd + lr;
      const int r7 = row & 7;
      bf16x8 v0 = *(const bf16x8*)(vsb + row * 64 + ((lg ^ r7) & 7) * 8);
      bf16x8 v1 = *(const bf16x8*)(vsb + row * 64 + (((4 + lg) ^ r7) & 7) * 8);
      accP[fd] = __builtin_amdgcn_mfma_f32_16x16x32_bf16(pa0, v0, accP[fd], 0, 0, 0);
      accP[fd] = __builtin_amdgcn_mfma_f32_16x16x32_bf16(pa1, v1, accP[fd], 0, 0, 0);
      accR[fd] = __builtin_amdgcn_mfma_f32_16x16x32_bf16(af[0], v0, accR[fd], 0, 0, 0);
      accR[fd] = __builtin_amdgcn_mfma_f32_16x16x32_bf16(af[1], v1, accR[fd], 0, 0, 0);
    }
    __builtin_amdgcn_s_setprio(0);

    // G) retire this iter's 4 gl16 (issued a full compute phase ago); rcs flies on
    __builtin_amdgcn_sched_barrier(0);
    asm volatile("s_waitcnt vmcnt(4)");
    __builtin_amdgcn_s_barrier();
    __builtin_amdgcn_sched_barrier(0);
  }

  // lsum: sum the 4 lanes sharing this lr, then gather per-output-row sums
  lsum += __shfl_xor(lsum, 16);
  lsum += __shfl_xor(lsum, 32);
  float ls[4];
  #pragma unroll
  for (int r = 0; r < 4; ++r) ls[r] = __shfl(lsum, 4 * lg + r);

  const int b = bh >> 4, hh = bh & 15;
  #pragma unroll
  for (int fd = 0; fd < 4; ++fd) {
    #pragma unroll
    for (int r = 0; r < 4; ++r) {
      const int irow = i_base + lg * 4 + r;
      if (irow < NSEQ) {
        const float val = 0.8f * accP[fd][r] / ls[r] + 1.2f * accR[fd][r];
        outp[(size_t)(b * NSEQ + irow) * CDIM + hh * 64 + 16 * fd + lr] = f2bf(val);
      }
    }
  }
}

extern "C" void kernel_launch(void* const* d_in, const int* in_sizes, int n_in,
                              void* d_out, int out_size, void* d_ws, size_t ws_size,
                              hipStream_t stream) {
  (void)in_sizes; (void)n_in; (void)out_size; (void)ws_size;
  const float* x      = (const float*)d_in[0];
  const float* qkv_w  = (const float*)d_in[1];
  const float* qkv_b  = (const float*)d_in[2];
  const float* proj_w = (const float*)d_in[3];
  const float* proj_b = (const float*)d_in[4];
  const float* rcs    = (const float*)d_in[6];
  float* out = (float*)d_out;

  char* ws = (char*)d_ws;
  unsigned short* x_bf = (unsigned short*)ws; ws += (size_t)BROWS * CDIM * 2;
  unsigned short* wkv  = (unsigned short*)ws; ws += (size_t)2048 * CDIM * 2;
  unsigned short* wp   = (unsigned short*)ws; ws += (size_t)1024 * CDIM * 2;
  unsigned short* Kb   = (unsigned short*)ws; ws += (size_t)64 * NSEQ * HD * 2;
  unsigned short* Vt   = (unsigned short*)ws; ws += (size_t)64 * HD * NSEQ * 2;
  unsigned short* op   = (unsigned short*)ws; ws += (size_t)BROWS * CDIM * 2;

  const int n1 = BROWS * CDIM / 4, n2 = 2048 * CDIM / 4, n3 = 1024 * CDIM / 4;
  convert_f32_bf16<<<(n1 + 255) / 256, 256, 0, stream>>>(x, x_bf, n1);
  convert_f32_bf16<<<(n2 + 255) / 256, 256, 0, stream>>>(qkv_w + 1024 * 1024, wkv, n2);
  convert_f32_bf16<<<(n3 + 255) / 256, 256, 0, stream>>>(proj_w, wp, n3);

  gemm_bt<0><<<dim3(16, 33), 256, 0, stream>>>(x_bf, wkv, qkv_b + 1024, Kb, Vt, nullptr, BROWS, CDIM);
  attn_fused<<<1088, 256, 0, stream>>>(Kb, Vt, rcs, op);
  gemm_bt<1><<<dim3(8, 33), 256, 0, stream>>>(op, wp, proj_b, nullptr, nullptr, out, BROWS, CDIM);
}